// Round 3
// baseline (371.883 us; speedup 1.0000x reference)
//
#include <hip/hip_runtime.h>
#include <math.h>

#pragma clang fp contract(off)

#define N_ROIS     1500
#define NUM_CLS    81
#define FG         80
#define MAXC       1536      // per-class valid-candidate capacity (worst case N_ROIS)
#define SORT_MAX   2048
#define NMS_T      0.5f
#define SCORE_T    0.05f
#define MAX_DET    100
#define TOTAL      (FG * N_ROIS)
#define LDS_STAGE  12288     // topk LDS staging capacity (floats)

// float <-> order-preserving uint
__device__ __forceinline__ unsigned f2s(float f) {
    unsigned u = __float_as_uint(f);
    return (u & 0x80000000u) ? ~u : (u | 0x80000000u);
}
__device__ __forceinline__ float s2f(unsigned u) {
    return __uint_as_float((u & 0x80000000u) ? (u & 0x7FFFFFFFu) : ~u);
}

// One WAVE (64 threads) per foreground class.
// Compact valid (s > 0.05) candidates -> stable sort (score desc, idx asc)
// -> decode only valid boxes -> greedy NMS over valid subset -> push kept
// entries to a global compact list. Also zero-fills this class's output
// region (dets=0, cls_idx=c, keep=0); kept rows are patched by topk_scatter.
//
// Key fact making the compaction exact: all valid scores strictly exceed all
// invalid ones, so a valid entry's rank in the full stable descending sort
// equals its rank in the valid-only stable sort. Non-kept rows emit zeros, so
// only kept rows (a subset of valid) ever need boxes/scores.
__global__ __launch_bounds__(64) void nms_kernel(
    const float* __restrict__ rois,    // (N,5)
    const float* __restrict__ deltas,  // (N, 4*81)
    const float* __restrict__ prob,    // (N, 81)
    const float* __restrict__ iminfo,  // (1,3)
    float4* __restrict__ keptBox,
    int*    __restrict__ keptRow,
    float*  __restrict__ keptScore,
    int*    __restrict__ counter,
    float*  __restrict__ out)
{
    __shared__ unsigned long long key[SORT_MAX];                 // 16 KB
    __shared__ float ssc[MAXC];
    __shared__ float bx1[MAXC], by1[MAXC], bx2[MAXC], by2[MAXC], bar[MAXC]; // 36 KB w/ ssc
    __shared__ unsigned char supp[MAXC], keepf[MAXC];            // 3 KB
    __shared__ int mcnt;

    const int lane = threadIdx.x;
    const int c = blockIdx.x + 1;   // class 1..80
    const int cbase = blockIdx.x * N_ROIS;

    if (lane == 0) mcnt = 0;
    __syncthreads();

    // --- compact valid candidates; key = score desc, idx asc (stable) ---
    for (int i = lane; i < N_ROIS; i += 64) {
        float s = prob[i * NUM_CLS + c];
        if (s > SCORE_T) {
            int p = atomicAdd(&mcnt, 1);
            key[p] = ((unsigned long long)(~f2s(s)) << 32) | (unsigned)i;
        }
    }
    __syncthreads();
    const int M = mcnt;

    // --- zero-fill this class's output region (overlaps nothing we need) ---
    {
        float* detsR = out + (size_t)cbase * 6;
        for (int i = lane; i < N_ROIS * 6; i += 64) detsR[i] = 0.0f;
        float* clsO  = out + (size_t)TOTAL * 6 + cbase;
        float* keepO = out + (size_t)TOTAL * 7 + cbase;
        const float fc = (float)c;
        for (int i = lane; i < N_ROIS; i += 64) { clsO[i] = fc; keepO[i] = 0.0f; }
    }

    if (M > 0) {
        // pad to next pow2
        int SN = 2; while (SN < M) SN <<= 1;
        for (int i = M + lane; i < SN; i += 64) key[i] = 0xFFFFFFFFFFFFFFFFull;
        __syncthreads();

        // bitonic sort, ascending keys
        for (unsigned k = 2; k <= (unsigned)SN; k <<= 1) {
            for (unsigned j = k >> 1; j > 0; j >>= 1) {
                __syncthreads();
                for (unsigned i = lane; i < (unsigned)SN; i += 64) {
                    unsigned ixj = i ^ j;
                    if (ixj > i) {
                        unsigned long long a = key[i], b = key[ixj];
                        bool up = ((i & k) == 0);
                        if ((a > b) == up) { key[i] = b; key[ixj] = a; }
                    }
                }
            }
        }
        __syncthreads();

        // --- decode boxes at sorted valid positions (match numpy op-for-op) ---
        const float Hm1 = iminfo[0] - 1.0f;
        const float Wm1 = iminfo[1] - 1.0f;
        for (int k = lane; k < M; k += 64) {
            unsigned long long kk = key[k];
            int i = (int)(kk & 0xFFFFFFFFu);
            ssc[k] = s2f(~(unsigned)(kk >> 32));
            const float* rp = rois + i * 5;
            float x1 = rp[1], y1 = rp[2], x2 = rp[3], y2 = rp[4];
            float w  = x2 - x1 + 1.0f;
            float h  = y2 - y1 + 1.0f;
            float cx = x1 + 0.5f * w;
            float cy = y1 + 0.5f * h;
            const float* dp = deltas + i * (4 * NUM_CLS) + c * 4;
            float dx = dp[0] / 10.0f, dy = dp[1] / 10.0f;
            float dw = dp[2] / 5.0f,  dh = dp[3] / 5.0f;
            float pcx = cx + w * dx;
            float pcy = cy + h * dy;
            float pw  = w * expf(dw);
            float ph  = h * expf(dh);
            float a1 = pcx - 0.5f * pw;
            float a2 = pcy - 0.5f * ph;
            float a3 = pcx + 0.5f * pw - 1.0f;
            float a4 = pcy + 0.5f * ph - 1.0f;
            a1 = fminf(fmaxf(a1, 0.0f), Wm1);
            a2 = fminf(fmaxf(a2, 0.0f), Hm1);
            a3 = fminf(fmaxf(a3, 0.0f), Wm1);
            a4 = fminf(fmaxf(a4, 0.0f), Hm1);
            bx1[k] = a1; by1[k] = a2; bx2[k] = a3; by2[k] = a4;
            bar[k] = (a3 - a1 + 1.0f) * (a4 - a2 + 1.0f);
            supp[k] = 0; keepf[k] = 0;
        }
        __syncthreads();

        // --- greedy NMS over valid subset (all M entries pass score test) ---
        for (int k = 0; k < M; ++k) {
            if (!supp[k]) {
                if (lane == 0) keepf[k] = 1;
                float x1 = bx1[k], y1 = by1[k], x2 = bx2[k], y2 = by2[k], ar = bar[k];
                for (int j = k + 1 + lane; j < M; j += 64) {
                    float iw = fminf(x2, bx2[j]) - fmaxf(x1, bx1[j]) + 1.0f;
                    float ih = fminf(y2, by2[j]) - fmaxf(y1, by1[j]) + 1.0f;
                    iw = fmaxf(iw, 0.0f);
                    ih = fmaxf(ih, 0.0f);
                    float inter = iw * ih;
                    float iou = inter / ((ar + bar[j]) - inter);
                    if (iou > NMS_T) supp[j] = 1;
                }
            }
            __syncthreads();
        }

        // --- push kept entries to global compact list ---
        for (int k = lane; k < M; k += 64) {
            if (keepf[k]) {
                int p = atomicAdd(counter, 1);
                keptRow[p]   = cbase + k;
                keptBox[p]   = make_float4(bx1[k], by1[k], bx2[k], by2[k]);
                keptScore[p] = ssc[k];
            }
        }
    }
}

// Single wave: exact 100th-largest kept score (32-bit MSB radix select,
// shuffle-only reductions, LDS-staged scores) + scatter kept rows into out.
__global__ __launch_bounds__(64) void topk_scatter(
    const int*    __restrict__ counter,
    const int*    __restrict__ keptRow,
    const float4* __restrict__ keptBox,
    const float*  __restrict__ keptScore,
    float* __restrict__ out)
{
    __shared__ unsigned sbits[LDS_STAGE];   // 48 KB
    const int lane = threadIdx.x;
    const int n = *counter;
    const bool filt = (n > MAX_DET);
    float kth = -INFINITY;

    if (filt) {
        const bool useLds = (n <= LDS_STAGE);
        if (useLds) {
            for (int i = lane; i < n; i += 64) sbits[i] = f2s(keptScore[i]);
        }
        __syncthreads();
        unsigned prefix = 0;
        int kk = MAX_DET;
        for (int b = 31; b >= 0; --b) {
            int c1 = 0;
            for (int i = lane; i < n; i += 64) {
                unsigned u = useLds ? sbits[i] : f2s(keptScore[i]);
                unsigned hi = (b == 31) ? 0u : (u >> (b + 1));
                c1 += (int)(hi == prefix && ((u >> b) & 1u));
            }
            for (int off = 32; off > 0; off >>= 1) c1 += __shfl_down(c1, off, 64);
            int t = __shfl(c1, 0, 64);
            if (t >= kk) prefix = (prefix << 1) | 1u;
            else { kk -= t; prefix <<= 1; }
        }
        kth = s2f(prefix);
    }

    for (int i = lane; i < n; i += 64) {
        float s = keptScore[i];
        if (!filt || s >= kth) {
            int r = keptRow[i];
            float4 b4 = keptBox[i];
            float* d = out + (size_t)r * 6;
            d[1] = b4.x; d[2] = b4.y; d[3] = b4.z; d[4] = b4.w; d[5] = s;
            out[(size_t)TOTAL * 7 + r] = 1.0f;
        }
    }
}

extern "C" void kernel_launch(void* const* d_in, const int* in_sizes, int n_in,
                              void* d_out, int out_size, void* d_ws, size_t ws_size,
                              hipStream_t stream) {
    const float* rois   = (const float*)d_in[0];  // (1500,5)
    const float* deltas = (const float*)d_in[1];  // (1500,324)
    const float* prob   = (const float*)d_in[2];  // (1500,81)
    const float* iminfo = (const float*)d_in[3];  // (1,3)
    float* out = (float*)d_out;

    // workspace: float4 first for 16B alignment
    float4* keptBox   = (float4*)d_ws;                 // TOTAL entries
    int*    keptRow   = (int*)(keptBox + TOTAL);       // TOTAL
    float*  keptScore = (float*)(keptRow + TOTAL);     // TOTAL
    int*    counter   = (int*)(keptScore + TOTAL);     // 1

    hipMemsetAsync(counter, 0, sizeof(int), stream);
    nms_kernel<<<FG, 64, 0, stream>>>(rois, deltas, prob, iminfo,
                                      keptBox, keptRow, keptScore, counter, out);
    topk_scatter<<<1, 64, 0, stream>>>(counter, keptRow, keptBox, keptScore, out);
}

// Round 4
// 138.411 us; speedup vs baseline: 2.6868x; 2.6868x over previous
//
#include <hip/hip_runtime.h>
#include <math.h>

#pragma clang fp contract(off)

#define N_ROIS     1500
#define NUM_CLS    81
#define FG         80
#define MAXC       1536      // per-class valid-candidate capacity (worst case N_ROIS)
#define SORT_MAX   2048
#define NMS_T      0.5f
#define SCORE_T    0.05f
#define MAX_DET    100
#define TOTAL      (FG * N_ROIS)

// float <-> order-preserving uint
__device__ __forceinline__ unsigned f2s(float f) {
    unsigned u = __float_as_uint(f);
    return (u & 0x80000000u) ? ~u : (u | 0x80000000u);
}
__device__ __forceinline__ float s2f(unsigned u) {
    return __uint_as_float((u & 0x80000000u) ? (u & 0x7FFFFFFFu) : ~u);
}

// One WAVE (64 threads) per foreground class.
// Compact valid (s > 0.05) candidates -> stable sort (score desc, idx asc)
// -> decode only valid boxes -> greedy NMS over valid subset -> push kept
// entries to a global compact list. Also zero-fills this class's output
// region (dets=0, cls_idx=c, keep=0); kept rows are patched by topk_scatter.
//
// Exactness of the compaction: all valid scores strictly exceed all invalid
// ones, so a valid entry's rank in the full stable descending sort equals its
// rank in the valid-only stable sort. Non-kept rows emit zeros, so only kept
// rows (subset of valid) ever need decoded boxes/scores.
__global__ __launch_bounds__(64) void nms_kernel(
    const float* __restrict__ rois,    // (N,5)
    const float* __restrict__ deltas,  // (N, 4*81)
    const float* __restrict__ prob,    // (N, 81)
    const float* __restrict__ iminfo,  // (1,3)
    float4* __restrict__ keptBox,
    int*    __restrict__ keptRow,
    float*  __restrict__ keptScore,
    int*    __restrict__ counter,
    float*  __restrict__ out)
{
    __shared__ unsigned long long key[SORT_MAX];                 // 16 KB
    __shared__ float ssc[MAXC];
    __shared__ float bx1[MAXC], by1[MAXC], bx2[MAXC], by2[MAXC], bar[MAXC]; // 36 KB w/ ssc
    __shared__ unsigned char supp[MAXC], keepf[MAXC];            // 3 KB
    __shared__ int mcnt;

    const int lane = threadIdx.x;
    const int c = blockIdx.x + 1;   // class 1..80
    const int cbase = blockIdx.x * N_ROIS;

    if (lane == 0) mcnt = 0;
    __syncthreads();

    // --- compact valid candidates; key = score desc, idx asc (stable) ---
    for (int i = lane; i < N_ROIS; i += 64) {
        float s = prob[i * NUM_CLS + c];
        if (s > SCORE_T) {
            int p = atomicAdd(&mcnt, 1);
            key[p] = ((unsigned long long)(~f2s(s)) << 32) | (unsigned)i;
        }
    }
    __syncthreads();
    const int M = mcnt;

    // --- zero-fill this class's output region (float4; all 16B-aligned) ---
    {
        const float4 z4 = make_float4(0.f, 0.f, 0.f, 0.f);
        float4* dets4 = (float4*)(out + (size_t)cbase * 6);       // 2250 exact
        for (int i = lane; i < N_ROIS * 6 / 4; i += 64) dets4[i] = z4;
        const float fc = (float)c;
        const float4 c4 = make_float4(fc, fc, fc, fc);
        float4* cls4  = (float4*)(out + (size_t)TOTAL * 6 + cbase); // 375 exact
        float4* keep4 = (float4*)(out + (size_t)TOTAL * 7 + cbase);
        for (int i = lane; i < N_ROIS / 4; i += 64) { cls4[i] = c4; keep4[i] = z4; }
    }

    if (M > 0) {
        // pad to next pow2
        int SN = 2; while (SN < M) SN <<= 1;
        for (int i = M + lane; i < SN; i += 64) key[i] = 0xFFFFFFFFFFFFFFFFull;
        __syncthreads();

        // bitonic sort, ascending keys
        for (unsigned k = 2; k <= (unsigned)SN; k <<= 1) {
            for (unsigned j = k >> 1; j > 0; j >>= 1) {
                __syncthreads();
                for (unsigned i = lane; i < (unsigned)SN; i += 64) {
                    unsigned ixj = i ^ j;
                    if (ixj > i) {
                        unsigned long long a = key[i], b = key[ixj];
                        bool up = ((i & k) == 0);
                        if ((a > b) == up) { key[i] = b; key[ixj] = a; }
                    }
                }
            }
        }
        __syncthreads();

        // --- decode boxes at sorted valid positions (match numpy op-for-op) ---
        const float Hm1 = iminfo[0] - 1.0f;
        const float Wm1 = iminfo[1] - 1.0f;
        for (int k = lane; k < M; k += 64) {
            unsigned long long kk = key[k];
            int i = (int)(kk & 0xFFFFFFFFu);
            ssc[k] = s2f(~(unsigned)(kk >> 32));
            const float* rp = rois + i * 5;
            float x1 = rp[1], y1 = rp[2], x2 = rp[3], y2 = rp[4];
            float w  = x2 - x1 + 1.0f;
            float h  = y2 - y1 + 1.0f;
            float cx = x1 + 0.5f * w;
            float cy = y1 + 0.5f * h;
            const float* dp = deltas + i * (4 * NUM_CLS) + c * 4;
            float dx = dp[0] / 10.0f, dy = dp[1] / 10.0f;
            float dw = dp[2] / 5.0f,  dh = dp[3] / 5.0f;
            float pcx = cx + w * dx;
            float pcy = cy + h * dy;
            float pw  = w * expf(dw);
            float ph  = h * expf(dh);
            float a1 = pcx - 0.5f * pw;
            float a2 = pcy - 0.5f * ph;
            float a3 = pcx + 0.5f * pw - 1.0f;
            float a4 = pcy + 0.5f * ph - 1.0f;
            a1 = fminf(fmaxf(a1, 0.0f), Wm1);
            a2 = fminf(fmaxf(a2, 0.0f), Hm1);
            a3 = fminf(fmaxf(a3, 0.0f), Wm1);
            a4 = fminf(fmaxf(a4, 0.0f), Hm1);
            bx1[k] = a1; by1[k] = a2; bx2[k] = a3; by2[k] = a4;
            bar[k] = (a3 - a1 + 1.0f) * (a4 - a2 + 1.0f);
            supp[k] = 0; keepf[k] = 0;
        }
        __syncthreads();

        // --- greedy NMS over valid subset (all M entries pass score test) ---
        for (int k = 0; k < M; ++k) {
            if (!supp[k]) {
                if (lane == 0) keepf[k] = 1;
                float x1 = bx1[k], y1 = by1[k], x2 = bx2[k], y2 = by2[k], ar = bar[k];
                for (int j = k + 1 + lane; j < M; j += 64) {
                    float iw = fminf(x2, bx2[j]) - fmaxf(x1, bx1[j]) + 1.0f;
                    float ih = fminf(y2, by2[j]) - fmaxf(y1, by1[j]) + 1.0f;
                    iw = fmaxf(iw, 0.0f);
                    ih = fmaxf(ih, 0.0f);
                    float inter = iw * ih;
                    float iou = inter / ((ar + bar[j]) - inter);
                    if (iou > NMS_T) supp[j] = 1;
                }
            }
            __syncthreads();
        }

        // --- push kept entries to global compact list ---
        for (int k = lane; k < M; k += 64) {
            if (keepf[k]) {
                int p = atomicAdd(counter, 1);
                keptRow[p]   = cbase + k;
                keptBox[p]   = make_float4(bx1[k], by1[k], bx2[k], by2[k]);
                keptScore[p] = ssc[k];
            }
        }
    }
}

// One block, 1024 threads (16 waves): exact 100th-largest kept score via
// MSB-first radix-256 select (4 digit rounds, LDS histogram), then scatter
// kept rows into out. Tie-exact, order-independent.
__global__ __launch_bounds__(1024) void topk_scatter(
    const int*    __restrict__ counter,
    const int*    __restrict__ keptRow,
    const float4* __restrict__ keptBox,
    const float*  __restrict__ keptScore,
    float* __restrict__ out)
{
    __shared__ int hist[256];
    __shared__ int gsum[64];
    __shared__ unsigned s_pref;
    __shared__ int s_kk;

    const int tid = threadIdx.x;
    const int n = *counter;
    const bool filt = (n > MAX_DET);
    float kth = -INFINITY;

    if (filt) {
        if (tid == 0) { s_pref = 0u; s_kk = MAX_DET; }
        for (int d = 0; d < 4; ++d) {
            const int shift = 24 - 8 * d;
            if (tid < 256) hist[tid] = 0;
            __syncthreads();
            const unsigned pref = s_pref;   // digits selected so far
            for (int i = tid; i < n; i += 1024) {
                unsigned u = f2s(keptScore[i]);
                if (d == 0 || (u >> (shift + 8)) == pref)
                    atomicAdd(&hist[(u >> shift) & 255u], 1);
            }
            __syncthreads();
            // wave 0: 4-bin group sums (cross-lane via LDS within one wave
            // is ordered by instruction order — no barrier needed)
            if (tid < 64) {
                int g = tid;
                gsum[g] = hist[4*g] + hist[4*g+1] + hist[4*g+2] + hist[4*g+3];
            }
            if (tid == 0) {
                int kk = s_kk;
                int acc = 0;
                int g = 63;
                for (; g > 0; --g) {            // find group from top
                    int gs = gsum[g];
                    if (acc + gs >= kk) break;
                    acc += gs;
                }
                int v = 4 * g + 3;
                for (; v > 4 * g; --v) {        // find digit within group
                    int h = hist[v];
                    if (acc + h >= kk) break;
                    acc += h;
                }
                s_pref = (pref << 8) | (unsigned)v;
                s_kk = kk - acc;                // rank within matched subset
            }
            __syncthreads();
        }
        kth = s2f(s_pref);
    }

    for (int i = tid; i < n; i += 1024) {
        float s = keptScore[i];
        if (!filt || s >= kth) {
            int r = keptRow[i];
            float4 b4 = keptBox[i];
            float* dst = out + (size_t)r * 6;
            dst[1] = b4.x; dst[2] = b4.y; dst[3] = b4.z; dst[4] = b4.w; dst[5] = s;
            out[(size_t)TOTAL * 7 + r] = 1.0f;
        }
    }
}

extern "C" void kernel_launch(void* const* d_in, const int* in_sizes, int n_in,
                              void* d_out, int out_size, void* d_ws, size_t ws_size,
                              hipStream_t stream) {
    const float* rois   = (const float*)d_in[0];  // (1500,5)
    const float* deltas = (const float*)d_in[1];  // (1500,324)
    const float* prob   = (const float*)d_in[2];  // (1500,81)
    const float* iminfo = (const float*)d_in[3];  // (1,3)
    float* out = (float*)d_out;

    // workspace: float4 first for 16B alignment
    float4* keptBox   = (float4*)d_ws;                 // TOTAL entries
    int*    keptRow   = (int*)(keptBox + TOTAL);       // TOTAL
    float*  keptScore = (float*)(keptRow + TOTAL);     // TOTAL
    int*    counter   = (int*)(keptScore + TOTAL);     // 1

    hipMemsetAsync(counter, 0, sizeof(int), stream);
    nms_kernel<<<FG, 64, 0, stream>>>(rois, deltas, prob, iminfo,
                                      keptBox, keptRow, keptScore, counter, out);
    topk_scatter<<<1, 1024, 0, stream>>>(counter, keptRow, keptBox, keptScore, out);
}

// Round 5
// 108.890 us; speedup vs baseline: 3.4152x; 1.2711x over previous
//
#include <hip/hip_runtime.h>
#include <math.h>

#pragma clang fp contract(off)

#define N_ROIS     1500
#define NUM_CLS    81
#define FG         80
#define MAXC       1536      // per-class candidate capacity (worst case N_ROIS)
#define NMS_T      0.5f
#define SCORE_T    0.05f
#define MAX_DET    100
#define TOTAL      (FG * N_ROIS)
#define TPB        256
#define LDS_STAGE  12288

// float <-> order-preserving uint
__device__ __forceinline__ unsigned f2s(float f) {
    unsigned u = __float_as_uint(f);
    return (u & 0x80000000u) ? ~u : (u | 0x80000000u);
}
__device__ __forceinline__ float s2f(unsigned u) {
    return __uint_as_float((u & 0x80000000u) ? (u & 0x7FFFFFFFu) : ~u);
}

// One block (256 threads) per foreground class.
// compact valid (s > 0.05) -> rank-by-counting sort (score desc, idx asc,
// exact since keys unique) -> decode valid boxes -> bitmask NMS:
// precompute MxM suppression bit-matrix in parallel (ballot per 64-col
// chunk), then a register-only serial scan on wave 0. Fallback to the
// iterative supp-loop when the mask matrix exceeds LDS (M*ceil(M/64)>1536).
// Also zero-fills this class's output region; kept rows patched later.
__global__ __launch_bounds__(TPB) void nms_kernel(
    const float* __restrict__ rois,    // (N,5)
    const float* __restrict__ deltas,  // (N, 4*81)
    const float* __restrict__ prob,    // (N, 81)
    const float* __restrict__ iminfo,  // (1,3)
    float4* __restrict__ keptBox,
    int*    __restrict__ keptRow,
    float*  __restrict__ keptScore,
    int*    __restrict__ counter,
    float*  __restrict__ out)
{
    __shared__ unsigned long long key[MAXC];   // unsorted keys; later: mask matrix
    __shared__ unsigned long long skey[MAXC];  // rank-sorted keys
    __shared__ float4 box4[MAXC];
    __shared__ unsigned char keepf[MAXC], supp[MAXC];
    __shared__ int mcnt;                       // total ~51.3 KB

    const int tid = threadIdx.x;
    const int c = blockIdx.x + 1;   // class 1..80
    const int cbase = blockIdx.x * N_ROIS;

    if (tid == 0) mcnt = 0;
    __syncthreads();

    // --- compact valid candidates; key = score desc, idx asc (stable) ---
    // Valid scores all exceed invalid ones, so valid-only stable rank ==
    // full stable rank; non-kept rows emit zeros so only valid rows matter.
    for (int i = tid; i < N_ROIS; i += TPB) {
        float s = prob[i * NUM_CLS + c];
        if (s > SCORE_T) {
            int p = atomicAdd(&mcnt, 1);
            key[p] = ((unsigned long long)(~f2s(s)) << 32) | (unsigned)i;
        }
    }

    // --- zero-fill this class's output region (float4; all 16B-aligned) ---
    {
        const float4 z4 = make_float4(0.f, 0.f, 0.f, 0.f);
        float4* dets4 = (float4*)(out + (size_t)cbase * 6);         // 2250
        for (int i = tid; i < N_ROIS * 6 / 4; i += TPB) dets4[i] = z4;
        const float fc = (float)c;
        const float4 c4 = make_float4(fc, fc, fc, fc);
        float4* cls4  = (float4*)(out + (size_t)TOTAL * 6 + cbase); // 375
        float4* keep4 = (float4*)(out + (size_t)TOTAL * 7 + cbase);
        for (int i = tid; i < N_ROIS / 4; i += TPB) { cls4[i] = c4; keep4[i] = z4; }
    }
    __syncthreads();
    const int M = mcnt;
    if (M == 0) return;

    // --- rank-by-counting sort: keys unique -> ranks form a permutation ---
    for (int i = tid; i < M; i += TPB) {
        unsigned long long kk = key[i];
        int cnt = 0;
        #pragma unroll 4
        for (int j = 0; j < M; ++j) cnt += (int)(key[j] < kk);
        skey[cnt] = kk;
    }
    __syncthreads();

    // --- decode boxes at sorted positions (match numpy op-for-op) ---
    const float Hm1 = iminfo[0] - 1.0f;
    const float Wm1 = iminfo[1] - 1.0f;
    for (int k = tid; k < M; k += TPB) {
        unsigned long long kk = skey[k];
        int i = (int)(kk & 0xFFFFFFFFu);
        const float* rp = rois + i * 5;
        float x1 = rp[1], y1 = rp[2], x2 = rp[3], y2 = rp[4];
        float w  = x2 - x1 + 1.0f;
        float h  = y2 - y1 + 1.0f;
        float cx = x1 + 0.5f * w;
        float cy = y1 + 0.5f * h;
        const float* dp = deltas + i * (4 * NUM_CLS) + c * 4;
        float dx = dp[0] / 10.0f, dy = dp[1] / 10.0f;
        float dw = dp[2] / 5.0f,  dh = dp[3] / 5.0f;
        float pcx = cx + w * dx;
        float pcy = cy + h * dy;
        float pw  = w * expf(dw);
        float ph  = h * expf(dh);
        float a1 = pcx - 0.5f * pw;
        float a2 = pcy - 0.5f * ph;
        float a3 = pcx + 0.5f * pw - 1.0f;
        float a4 = pcy + 0.5f * ph - 1.0f;
        a1 = fminf(fmaxf(a1, 0.0f), Wm1);
        a2 = fminf(fmaxf(a2, 0.0f), Hm1);
        a3 = fminf(fmaxf(a3, 0.0f), Wm1);
        a4 = fminf(fmaxf(a4, 0.0f), Hm1);
        box4[k] = make_float4(a1, a2, a3, a4);
        keepf[k] = 0; supp[k] = 0;
    }
    __syncthreads();

    const int MW = (M + 63) >> 6;          // 64-bit words per mask row
    const bool fast = (M * MW <= MAXC);    // mask matrix fits in key[]

    if (fast) {
        // --- suppression bit-matrix: row r, bit j set iff j>r && iou>0.5 ---
        const int wave = tid >> 6, lane = tid & 63;
        for (int r = wave; r < M; r += TPB / 64) {
            float4 br = box4[r];
            float ar = (br.z - br.x + 1.0f) * (br.w - br.y + 1.0f);
            for (int w = 0; w < MW; ++w) {
                int col = (w << 6) | lane;
                int j = col < M ? col : M - 1;
                float4 bj = box4[j];
                float aj = (bj.z - bj.x + 1.0f) * (bj.w - bj.y + 1.0f);
                float iw = fminf(br.z, bj.z) - fmaxf(br.x, bj.x) + 1.0f;
                float ih = fminf(br.w, bj.w) - fmaxf(br.y, bj.y) + 1.0f;
                iw = fmaxf(iw, 0.0f);
                ih = fmaxf(ih, 0.0f);
                float inter = iw * ih;
                float iou = inter / ((ar + aj) - inter);
                bool pred = (col > r) && (col < M) && (iou > NMS_T);
                unsigned long long m = __ballot(pred);
                if (lane == 0) key[r * MW + w] = m;
            }
        }
        __syncthreads();

        // --- serial scan, wave 0, register-only chain ---
        if (tid < 64) {
            const int lw = (tid < MW) ? tid : 0;
            unsigned long long acc = 0;   // suppressed bits, word `tid`
            for (int k = 0; k < M; ++k) {
                unsigned long long m = key[k * MW + lw];   // prefetchable
                int bit = (int)((acc >> (k & 63)) & 1ull);
                int sup = __shfl(bit, k >> 6, 64);
                if (!sup) {                // wave-uniform branch
                    acc |= m;
                    if (tid == 0) keepf[k] = 1;
                }
            }
        }
        __syncthreads();
    } else {
        // --- fallback: iterative greedy NMS (correct for any M) ---
        for (int k = 0; k < M; ++k) {
            if (!supp[k]) {
                if (tid == 0) keepf[k] = 1;
                float4 bk = box4[k];
                float ak = (bk.z - bk.x + 1.0f) * (bk.w - bk.y + 1.0f);
                for (int j = k + 1 + tid; j < M; j += TPB) {
                    float4 bj = box4[j];
                    float aj = (bj.z - bj.x + 1.0f) * (bj.w - bj.y + 1.0f);
                    float iw = fminf(bk.z, bj.z) - fmaxf(bk.x, bj.x) + 1.0f;
                    float ih = fminf(bk.w, bj.w) - fmaxf(bk.y, bj.y) + 1.0f;
                    iw = fmaxf(iw, 0.0f);
                    ih = fmaxf(ih, 0.0f);
                    float inter = iw * ih;
                    float iou = inter / ((ak + aj) - inter);
                    if (iou > NMS_T) supp[j] = 1;
                }
            }
            __syncthreads();
        }
    }

    // --- push kept entries to global compact list ---
    for (int k = tid; k < M; k += TPB) {
        if (keepf[k]) {
            int p = atomicAdd(counter, 1);
            keptRow[p]   = cbase + k;
            keptBox[p]   = box4[k];
            keptScore[p] = s2f(~(unsigned)(skey[k] >> 32));
        }
    }
}

// One block, 1024 threads: exact 100th-largest kept score via MSB-first
// radix-256 select (4 rounds, LDS histogram, LDS-staged score bits), then
// scatter kept rows into out. Tie-exact, order-independent.
__global__ __launch_bounds__(1024) void topk_scatter(
    const int*    __restrict__ counter,
    const int*    __restrict__ keptRow,
    const float4* __restrict__ keptBox,
    const float*  __restrict__ keptScore,
    float* __restrict__ out)
{
    __shared__ unsigned sbits[LDS_STAGE];   // 48 KB
    __shared__ int hist[256];
    __shared__ int gsum[64];
    __shared__ unsigned s_pref;
    __shared__ int s_kk;

    const int tid = threadIdx.x;
    const int n = *counter;
    const bool filt = (n > MAX_DET);
    float kth = -INFINITY;

    if (filt) {
        const bool useLds = (n <= LDS_STAGE);
        if (useLds)
            for (int i = tid; i < n; i += 1024) sbits[i] = f2s(keptScore[i]);
        if (tid == 0) { s_pref = 0u; s_kk = MAX_DET; }
        __syncthreads();
        for (int d = 0; d < 4; ++d) {
            const int shift = 24 - 8 * d;
            if (tid < 256) hist[tid] = 0;
            __syncthreads();
            const unsigned pref = s_pref;
            for (int i = tid; i < n; i += 1024) {
                unsigned u = useLds ? sbits[i] : f2s(keptScore[i]);
                if (d == 0 || (u >> (shift + 8)) == pref)
                    atomicAdd(&hist[(u >> shift) & 255u], 1);
            }
            __syncthreads();
            if (tid < 64) {
                int g = tid;
                gsum[g] = hist[4*g] + hist[4*g+1] + hist[4*g+2] + hist[4*g+3];
            }
            if (tid == 0) {
                int kk = s_kk;
                int acc = 0;
                int g = 63;
                for (; g > 0; --g) {
                    int gs = gsum[g];
                    if (acc + gs >= kk) break;
                    acc += gs;
                }
                int v = 4 * g + 3;
                for (; v > 4 * g; --v) {
                    int h = hist[v];
                    if (acc + h >= kk) break;
                    acc += h;
                }
                s_pref = (pref << 8) | (unsigned)v;
                s_kk = kk - acc;
            }
            __syncthreads();
        }
        kth = s2f(s_pref);
    }

    for (int i = tid; i < n; i += 1024) {
        float s = keptScore[i];
        if (!filt || s >= kth) {
            int r = keptRow[i];
            float4 b4 = keptBox[i];
            float* dst = out + (size_t)r * 6;
            dst[1] = b4.x; dst[2] = b4.y; dst[3] = b4.z; dst[4] = b4.w; dst[5] = s;
            out[(size_t)TOTAL * 7 + r] = 1.0f;
        }
    }
}

extern "C" void kernel_launch(void* const* d_in, const int* in_sizes, int n_in,
                              void* d_out, int out_size, void* d_ws, size_t ws_size,
                              hipStream_t stream) {
    const float* rois   = (const float*)d_in[0];  // (1500,5)
    const float* deltas = (const float*)d_in[1];  // (1500,324)
    const float* prob   = (const float*)d_in[2];  // (1500,81)
    const float* iminfo = (const float*)d_in[3];  // (1,3)
    float* out = (float*)d_out;

    // workspace: float4 first for 16B alignment
    float4* keptBox   = (float4*)d_ws;                 // TOTAL entries
    int*    keptRow   = (int*)(keptBox + TOTAL);       // TOTAL
    float*  keptScore = (float*)(keptRow + TOTAL);     // TOTAL
    int*    counter   = (int*)(keptScore + TOTAL);     // 1

    hipMemsetAsync(counter, 0, sizeof(int), stream);
    nms_kernel<<<FG, TPB, 0, stream>>>(rois, deltas, prob, iminfo,
                                       keptBox, keptRow, keptScore, counter, out);
    topk_scatter<<<1, 1024, 0, stream>>>(counter, keptRow, keptBox, keptScore, out);
}